// Round 1
// baseline (725.674 us; speedup 1.0000x reference)
//
#include <hip/hip_runtime.h>
#include <cstdint>
#include <cmath>

#define N_HEADS 16
#define I_DIM 128
#define H_DIM 128
#define B_SZ 16
#define T_SZ 512
#define G3 384           // 3*H
#define BT (B_SZ * T_SZ) // 8192
#define LDW 136          // padded LDS row stride in bf16 (128+8), keeps 16B align
#define OUT_HN_OFFSET ((size_t)B_SZ * T_SZ * (N_HEADS * H_DIM)) // 16777216

typedef __attribute__((ext_vector_type(8))) short bf16x8;
typedef __attribute__((ext_vector_type(4))) float f32x4;

static __device__ __forceinline__ unsigned short f2bf(float f) {
  unsigned int u = __float_as_uint(f);
  unsigned int r = (u + 0x7FFFu + ((u >> 16) & 1u)) >> 16; // RNE
  return (unsigned short)r;
}
static __device__ __forceinline__ float bf2f(unsigned short s) {
  return __uint_as_float((unsigned int)s << 16);
}
static __device__ __forceinline__ uint2 pack4(float4 v) {
  uint2 p;
  p.x = (unsigned int)f2bf(v.x) | ((unsigned int)f2bf(v.y) << 16);
  p.y = (unsigned int)f2bf(v.z) | ((unsigned int)f2bf(v.w) << 16);
  return p;
}

// LDS-only workgroup barrier. __syncthreads() emits
//   s_waitcnt vmcnt(0) lgkmcnt(0); s_barrier
// the vmcnt(0) drains outstanding GLOBAL stores (out / gates epilogue) and
// prefetch loads at every barrier, putting full HBM store-ack latency on the
// per-step critical path. Nothing crossing our barriers needs global
// ordering (out is write-only; prefetched gates are consumed via
// compiler-counted vmcnt waits), so wait on LDS only. The single asm block
// with a "memory" clobber is a full compiler fence: no LDS op can be moved
// across it, and values cached from LDS are reloaded after it.
static __device__ __forceinline__ void bar_lds() {
  asm volatile("s_waitcnt lgkmcnt(0)\n\ts_barrier" ::: "memory");
}

// ---------------------------------------------------------------------------
// Kernel A: bf16 MFMA GEMM, gates stored as bf16.
// v2: grid = (16 bt-groups) x (16 heads) = 256 WGs (1/CU). Each WG converts
// and stages ALL of W_ih[n] (384x128 -> 104 KB LDS) ONCE, then loops over 8
// X tiles of 64(bt)x128(k). The old layout restaged+repacked W per bt-block
// (128x redundancy -> ~100M f32->bf16 packs); that VALU was the kernel's
// bottleneck. X tiles are register-prefetched so the global latency hides
// under MFMA. Arithmetic (fragment order, pack4 RNE, bias add) is bitwise
// identical to v1 -> identical gates.
// ---------------------------------------------------------------------------
__global__ __launch_bounds__(256) void gates_x_mfma(
    const float* __restrict__ x, const float* __restrict__ w_ih,
    const float* __restrict__ b_ih, unsigned short* __restrict__ gates) {
  const int n = blockIdx.z;
  const int grp = blockIdx.x; // 0..15, 8 tiles of 64 bt-rows each
  const int tid = threadIdx.x;
  const int wave = tid >> 6;
  const int lane = tid & 63;
  const int m16 = lane & 15;
  const int quad = lane >> 4;

  extern __shared__ __align__(16) unsigned short lds_pool[];
  unsigned short* Ws = lds_pool;            // G3*LDW ushorts = 104,448 B
  unsigned short* Xs = lds_pool + G3 * LDW; // 64*LDW ushorts =  17,408 B

  const int xrow = tid >> 2;
  const int xq = tid & 3;

  // Prefetch first X tile into regs (overlaps the W convert below).
  float4 xf[8];
  {
    const float4* xg =
        (const float4*)(x + (size_t)(grp * 512 + xrow) * 2048 + n * I_DIM) +
        xq * 8;
#pragma unroll
    for (int i = 0; i < 8; ++i) xf[i] = xg[i];
  }

  // Stage + convert ALL of W_ih[n]: 12288 float4, lane-consecutive (coalesced).
  {
    const float4* wsrc = (const float4*)(w_ih + (size_t)n * G3 * I_DIM);
#pragma unroll
    for (int i = 0; i < 48; ++i) {
      const int idx = i * 256 + tid;                         // f4 index
      *(uint2*)&Ws[(idx >> 5) * LDW + (idx & 31) * 4] = pack4(wsrc[idx]);
    }
  }

  // Per-thread bias registers (3 gate-blocks x 8 col-frags).
  float bias[3][8];
#pragma unroll
  for (int gb = 0; gb < 3; ++gb)
#pragma unroll
    for (int j = 0; j < 8; ++j)
      bias[gb][j] = b_ih[n * G3 + gb * 128 + j * 16 + m16];

  for (int tile = 0; tile < 8; ++tile) {
    const int bt0 = grp * 512 + tile * 64;

    bar_lds(); // tile 0: Ws staged; tile>0: all Xs reads of prior tile done
#pragma unroll
    for (int i = 0; i < 8; ++i)
      *(uint2*)&Xs[xrow * LDW + xq * 32 + i * 4] = pack4(xf[i]);
    bar_lds(); // Xs visible

    // Prefetch next tile (overlaps MFMA + epilogue).
    if (tile < 7) {
      const float4* xg =
          (const float4*)(x + (size_t)(bt0 + 64 + xrow) * 2048 + n * I_DIM) +
          xq * 8;
#pragma unroll
      for (int i = 0; i < 8; ++i) xf[i] = xg[i];
    }

#pragma unroll
    for (int gb = 0; gb < 3; ++gb) {
      f32x4 acc[8];
#pragma unroll
      for (int j = 0; j < 8; ++j) acc[j] = (f32x4){0.f, 0.f, 0.f, 0.f};

#pragma unroll
      for (int kt = 0; kt < 4; ++kt) {
        const bf16x8 afrag =
            *(const bf16x8*)&Xs[(wave * 16 + m16) * LDW + kt * 32 + quad * 8];
#pragma unroll
        for (int j = 0; j < 8; ++j) {
          const bf16x8 bfrag =
              *(const bf16x8*)&Ws[(gb * 128 + j * 16 + m16) * LDW + kt * 32 +
                                  quad * 8];
          acc[j] = __builtin_amdgcn_mfma_f32_16x16x32_bf16(afrag, bfrag,
                                                           acc[j], 0, 0, 0);
        }
      }

      // Epilogue: bias + bf16 store. D[row=quad*4+r][col=m16].
#pragma unroll
      for (int j = 0; j < 8; ++j) {
        const int g = gb * 128 + j * 16 + m16;
#pragma unroll
        for (int r = 0; r < 4; ++r) {
          const int bt = bt0 + wave * 16 + quad * 4 + r;
          gates[((size_t)n * BT + bt) * G3 + g] =
              f2bf(acc[j][r] + bias[gb][j]);
        }
      }
    }
  }
}

// ---------------------------------------------------------------------------
// Kernel B: sequential GRU scan. One WG per (b,n). 768 thr = 12 waves.
// Wave w handles gates [(w>>1)*64 .. +64) with K-half (w&1): per k-step the
// whole wave reads ONE float4 of h (wave-uniform address -> free broadcast).
// v2 changes vs the 521us version:
//  * bar_lds() instead of __syncthreads(): the per-step `out` HBM store no
//    longer serializes at barrier 2 (it was a naked ~500-900 cycle vmcnt(0)
//    drain each step, waited on by all 12 waves).
//  * h_old kept in a register by the update threads (thread tid is the only
//    writer of h_lds[tid]) -> removes an LDS read from the update chain.
// Numerics identical to v1.
// ---------------------------------------------------------------------------
__global__ __launch_bounds__(768, 1) void gru_scan_kernel(
    const float* __restrict__ h0, const float* __restrict__ w_hh,
    const float* __restrict__ b_hh, const unsigned short* __restrict__ gates,
    float* __restrict__ out) {
  const int b = blockIdx.x >> 4;
  const int n = blockIdx.x & 15;
  const int tid = threadIdx.x;
  const int wave = tid >> 6;
  const int lane = tid & 63;
  const int half = wave & 1;
  const int g = ((wave >> 1) << 6) + lane; // 0..383

  __shared__ float h_lds[H_DIM];
  __shared__ float part[2][G3];

  const float4* w4 =
      (const float4*)(w_hh + ((size_t)n * G3 + g) * H_DIM + half * 64);
  float4 w[16];
#pragma unroll
  for (int k = 0; k < 16; ++k) w[k] = w4[k];
#pragma unroll
  for (int k = 0; k < 16; ++k) {
    asm volatile("" : "+v"(w[k].x), "+v"(w[k].y), "+v"(w[k].z), "+v"(w[k].w));
  }

  // Update-thread constants (threads 0..127 own h element `tid`).
  float bh0 = 0.f, bh1 = 0.f, bh2 = 0.f, h_old = 0.f;
  if (tid < H_DIM) {
    bh0 = b_hh[n * G3 + tid];
    bh1 = b_hh[n * G3 + tid + 128];
    bh2 = b_hh[n * G3 + tid + 256];
    h_old = h0[(size_t)b * 2048 + n * H_DIM + tid];
    h_lds[tid] = h_old;
  }

  const unsigned short* gx_base =
      gates + ((size_t)n * BT + (size_t)b * T_SZ) * G3;
  float* out_base = out + (size_t)b * T_SZ * 2048 + n * H_DIM;

  float gxr = 0.f, gxz = 0.f, gxn = 0.f;
  if (tid < H_DIM) {
    gxr = bf2f(gx_base[tid]);
    gxz = bf2f(gx_base[tid + 128]);
    gxn = bf2f(gx_base[tid + 256]);
  }
  bar_lds();

  for (int t = 0; t < T_SZ; ++t) {
    // Prefetch next step's gates_x (consumed next iteration; the compiler's
    // counted vmcnt wait never has to drain the younger out-store).
    float pr = 0.f, pz = 0.f, pn = 0.f;
    const int tn = (t + 1 < T_SZ) ? t + 1 : t;
    if (tid < H_DIM) {
      const unsigned short* gx = gx_base + (size_t)tn * G3;
      pr = bf2f(gx[tid]);
      pz = bf2f(gx[tid + 128]);
      pn = bf2f(gx[tid + 256]);
    }

    // Dot: wave-uniform h reads (single-address broadcast).
    const float4* h4 = (const float4*)h_lds + half * 16;
    float a0 = 0.f, a1 = 0.f, a2 = 0.f, a3 = 0.f;
#pragma unroll
    for (int k = 0; k < 16; ++k) {
      const float4 hv = h4[k];
      a0 += w[k].x * hv.x;
      a1 += w[k].y * hv.y;
      a2 += w[k].z * hv.z;
      a3 += w[k].w * hv.w;
    }
    part[half][g] = (a0 + a1) + (a2 + a3);
    bar_lds();

    if (tid < H_DIM) {
      const float ghr = part[0][tid] + part[1][tid] + bh0;
      const float ghz = part[0][tid + 128] + part[1][tid + 128] + bh1;
      const float ghn = part[0][tid + 256] + part[1][tid + 256] + bh2;
      const float r = 1.f / (1.f + __expf(-(gxr + ghr)));
      const float z = 1.f / (1.f + __expf(-(gxz + ghz)));
      const float targ = gxn + r * ghn;
      const float e2 = __expf(-2.f * fabsf(targ));
      float nn = (1.f - e2) / (1.f + e2);
      nn = (targ < 0.f) ? -nn : nn;
      const float hn = (1.f - z) * nn + z * h_old;
      h_lds[tid] = hn;
      h_old = hn;
      out_base[(size_t)t * 2048 + tid] = hn; // floats: drains off-path now
    }
    gxr = pr; gxz = pz; gxn = pn;
    bar_lds();
  }

  if (tid < H_DIM) {
    out[OUT_HN_OFFSET + (size_t)b * 2048 + n * H_DIM + tid] = h_old;
  }
}

extern "C" void kernel_launch(void* const* d_in, const int* in_sizes, int n_in,
                              void* d_out, int out_size, void* d_ws,
                              size_t ws_size, hipStream_t stream) {
  const float* x    = (const float*)d_in[0]; // [B, T, N*I]
  const float* h0   = (const float*)d_in[1]; // [1, B, N*H]
  const float* w_ih = (const float*)d_in[2]; // [N, 3H, I]
  const float* w_hh = (const float*)d_in[3]; // [N, 3H, H]
  const float* b_ih = (const float*)d_in[4]; // [N, 3H]
  const float* b_hh = (const float*)d_in[5]; // [N, 3H]
  float* out = (float*)d_out;
  unsigned short* gates = (unsigned short*)d_ws; // [N][BT][3H] bf16 = 96 MB

  // Kernel A uses 122 KB LDS (full W_ih[n] resident): opt in past 64 KB.
  static bool lds_opt_in = false;
  if (!lds_opt_in) {
    (void)hipFuncSetAttribute(reinterpret_cast<const void*>(&gates_x_mfma),
                              hipFuncAttributeMaxDynamicSharedMemorySize,
                              (G3 + 64) * LDW * (int)sizeof(unsigned short));
    lds_opt_in = true;
  }

  dim3 gridA(16, 1, N_HEADS);
  gates_x_mfma<<<gridA, 256, (G3 + 64) * LDW * sizeof(unsigned short),
                 stream>>>(x, w_ih, b_ih, gates);
  gru_scan_kernel<<<256, 768, 0, stream>>>(h0, w_hh, b_hh, gates, out);
}

// Round 2
// 698.864 us; speedup vs baseline: 1.0384x; 1.0384x over previous
//
#include <hip/hip_runtime.h>
#include <cstdint>
#include <cmath>

#define N_HEADS 16
#define I_DIM 128
#define H_DIM 128
#define B_SZ 16
#define T_SZ 512
#define G3 384           // 3*H
#define BT (B_SZ * T_SZ) // 8192
#define LDW 136          // padded LDS row stride in bf16 (128+8), keeps 16B align
#define OUT_HN_OFFSET ((size_t)B_SZ * T_SZ * (N_HEADS * H_DIM)) // 16777216

typedef __attribute__((ext_vector_type(8))) short bf16x8;
typedef __attribute__((ext_vector_type(4))) float f32x4;

static __device__ __forceinline__ unsigned short f2bf(float f) {
  unsigned int u = __float_as_uint(f);
  unsigned int r = (u + 0x7FFFu + ((u >> 16) & 1u)) >> 16; // RNE
  return (unsigned short)r;
}
static __device__ __forceinline__ float bf2f(unsigned short s) {
  return __uint_as_float((unsigned int)s << 16);
}
static __device__ __forceinline__ uint2 pack4(float4 v) {
  uint2 p;
  p.x = (unsigned int)f2bf(v.x) | ((unsigned int)f2bf(v.y) << 16);
  p.y = (unsigned int)f2bf(v.z) | ((unsigned int)f2bf(v.w) << 16);
  return p;
}
static __device__ __forceinline__ bf16x8 pack8(float4 a, float4 b) {
  union { uint2 u[2]; bf16x8 v; } r;
  r.u[0] = pack4(a);
  r.u[1] = pack4(b);
  return r.v;
}

// ---------------------------------------------------------------------------
// Kernel A (unchanged from R1 — it improved ~30us): bf16 MFMA GEMM.
// grid = (16 bt-groups) x (16 heads) = 256 WGs (1/CU). Each WG converts and
// stages ALL of W_ih[n] (384x128 -> 104 KB LDS) ONCE, then loops over 8 X
// tiles of 64(bt)x128(k) with register-prefetched X.
// ---------------------------------------------------------------------------
__global__ __launch_bounds__(256) void gates_x_mfma(
    const float* __restrict__ x, const float* __restrict__ w_ih,
    const float* __restrict__ b_ih, unsigned short* __restrict__ gates) {
  const int n = blockIdx.z;
  const int grp = blockIdx.x; // 0..15, 8 tiles of 64 bt-rows each
  const int tid = threadIdx.x;
  const int wave = tid >> 6;
  const int lane = tid & 63;
  const int m16 = lane & 15;
  const int quad = lane >> 4;

  extern __shared__ __align__(16) unsigned short lds_pool[];
  unsigned short* Ws = lds_pool;            // G3*LDW ushorts = 104,448 B
  unsigned short* Xs = lds_pool + G3 * LDW; // 64*LDW ushorts =  17,408 B

  const int xrow = tid >> 2;
  const int xq = tid & 3;

  // Prefetch first X tile into regs (overlaps the W convert below).
  float4 xf[8];
  {
    const float4* xg =
        (const float4*)(x + (size_t)(grp * 512 + xrow) * 2048 + n * I_DIM) +
        xq * 8;
#pragma unroll
    for (int i = 0; i < 8; ++i) xf[i] = xg[i];
  }

  // Stage + convert ALL of W_ih[n]: 12288 float4, lane-consecutive (coalesced).
  {
    const float4* wsrc = (const float4*)(w_ih + (size_t)n * G3 * I_DIM);
#pragma unroll
    for (int i = 0; i < 48; ++i) {
      const int idx = i * 256 + tid;                         // f4 index
      *(uint2*)&Ws[(idx >> 5) * LDW + (idx & 31) * 4] = pack4(wsrc[idx]);
    }
  }

  // Per-thread bias registers (3 gate-blocks x 8 col-frags).
  float bias[3][8];
#pragma unroll
  for (int gb = 0; gb < 3; ++gb)
#pragma unroll
    for (int j = 0; j < 8; ++j)
      bias[gb][j] = b_ih[n * G3 + gb * 128 + j * 16 + m16];

  for (int tile = 0; tile < 8; ++tile) {
    const int bt0 = grp * 512 + tile * 64;

    __syncthreads(); // tile 0: Ws staged; tile>0: all Xs reads of prior tile done
#pragma unroll
    for (int i = 0; i < 8; ++i)
      *(uint2*)&Xs[xrow * LDW + xq * 32 + i * 4] = pack4(xf[i]);
    __syncthreads(); // Xs visible

    // Prefetch next tile (overlaps MFMA + epilogue).
    if (tile < 7) {
      const float4* xg =
          (const float4*)(x + (size_t)(bt0 + 64 + xrow) * 2048 + n * I_DIM) +
          xq * 8;
#pragma unroll
      for (int i = 0; i < 8; ++i) xf[i] = xg[i];
    }

#pragma unroll
    for (int gb = 0; gb < 3; ++gb) {
      f32x4 acc[8];
#pragma unroll
      for (int j = 0; j < 8; ++j) acc[j] = (f32x4){0.f, 0.f, 0.f, 0.f};

#pragma unroll
      for (int kt = 0; kt < 4; ++kt) {
        const bf16x8 afrag =
            *(const bf16x8*)&Xs[(wave * 16 + m16) * LDW + kt * 32 + quad * 8];
#pragma unroll
        for (int j = 0; j < 8; ++j) {
          const bf16x8 bfrag =
              *(const bf16x8*)&Ws[(gb * 128 + j * 16 + m16) * LDW + kt * 32 +
                                  quad * 8];
          acc[j] = __builtin_amdgcn_mfma_f32_16x16x32_bf16(afrag, bfrag,
                                                           acc[j], 0, 0, 0);
        }
      }

      // Epilogue: bias + bf16 store. D[row=quad*4+r][col=m16].
#pragma unroll
      for (int j = 0; j < 8; ++j) {
        const int g = gb * 128 + j * 16 + m16;
#pragma unroll
        for (int r = 0; r < 4; ++r) {
          const int bt = bt0 + wave * 16 + quad * 4 + r;
          gates[((size_t)n * BT + bt) * G3 + g] =
              f2bf(acc[j][r] + bias[gb][j]);
        }
      }
    }
  }
}

// ---------------------------------------------------------------------------
// Kernel B v3: MFMA-based GRU scan. One WG (256 thr = 4 waves) per (b,n).
//
// R1 post-mortem: the 12-wave broadcast-dot was DS-pipe-bound — 192
// wave-uniform ds_read_b128 per step (~12cy each ~ 2300cy) matched the
// measured 2440cy/step. (Also: inline-asm barriers regressed — LLVM flushes
// counters around memory-clobber asm anyway AND loses scheduling freedom.
// Plain __syncthreads() everywhere.)
//
// New structure: gates_h = W_hh[n] . h computed by MFMA with h REPLICATED
// across all 16 A-rows (A[r][k] = h[k] => every D row = gates_h). W_hh is
// register-resident bf16 (wave owns 6 16-gate colblocks = 96 VGPRs). Per
// step each wave does: 8 broadcast ds_read_b128 (h hi/lo) + 48 MFMA +
// 6 ds_write_b32 — DS traffic down ~20x.
//
// Precision: h is split hi/lo into two bf16 MFMA passes (W.(hh+hl)), so h
// carries ~16 mantissa bits; the only new rounding is W_hh->bf16 (~2^-9
// rel), an order below the existing bf16 gates_x quantization.
//
// The out[t] store is issued at the TOP of step t+1 so its vmcnt drain at
// the next __syncthreads retires under the MFMA phase, off the chain.
// ---------------------------------------------------------------------------
__global__ __launch_bounds__(256, 1) void gru_scan_kernel(
    const float* __restrict__ h0, const float* __restrict__ w_hh,
    const float* __restrict__ b_hh, const unsigned short* __restrict__ gates,
    float* __restrict__ out) {
  const int b = blockIdx.x >> 4;
  const int n = blockIdx.x & 15;
  const int tid = threadIdx.x;
  const int wave = tid >> 6;
  const int lane = tid & 63;
  const int m16 = lane & 15;
  const int quad = lane >> 4;

  __shared__ __align__(16) unsigned short h_hi[H_DIM];
  __shared__ __align__(16) unsigned short h_lo[H_DIM];
  __shared__ float part[G3];

  // Register-resident W_hh bf16 B-fragments. Layout matches kernel A's
  // verified bfrag: lane(quad,m16) holds W[g = cb*16+m16][kt*32+quad*8 ..+8].
  bf16x8 wf[6][4];
#pragma unroll
  for (int j = 0; j < 6; ++j) {
    const int g = (wave * 6 + j) * 16 + m16;
    const float4* wr = (const float4*)(w_hh + ((size_t)n * G3 + g) * H_DIM);
#pragma unroll
    for (int kt = 0; kt < 4; ++kt) {
      wf[j][kt] = pack8(wr[kt * 8 + quad * 2], wr[kt * 8 + quad * 2 + 1]);
    }
  }

  // Update-thread state (threads 0..127 own h element `tid`).
  float bh0 = 0.f, bh1 = 0.f, bh2 = 0.f, h_old = 0.f, hn_prev = 0.f;
  if (tid < H_DIM) {
    bh0 = b_hh[n * G3 + tid];
    bh1 = b_hh[n * G3 + tid + 128];
    bh2 = b_hh[n * G3 + tid + 256];
    h_old = h0[(size_t)b * 2048 + n * H_DIM + tid];
    const unsigned short hh = f2bf(h_old);
    h_hi[tid] = hh;
    h_lo[tid] = f2bf(h_old - bf2f(hh));
  }

  const unsigned short* gx_base =
      gates + ((size_t)n * BT + (size_t)b * T_SZ) * G3;
  float* out_base = out + (size_t)b * T_SZ * 2048 + n * H_DIM;

  float gxr = 0.f, gxz = 0.f, gxn = 0.f;
  if (tid < H_DIM) {
    gxr = bf2f(gx_base[tid]);
    gxz = bf2f(gx_base[tid + 128]);
    gxn = bf2f(gx_base[tid + 256]);
  }
  __syncthreads();

  for (int t = 0; t < T_SZ; ++t) {
    // Deferred output store: issued here so it retires under the MFMAs.
    if (tid < H_DIM && t > 0)
      out_base[(size_t)(t - 1) * 2048 + tid] = hn_prev;

    // Prefetch next step's gates_x (consumed next iteration).
    float pr = 0.f, pz = 0.f, pn = 0.f;
    const int tn = (t + 1 < T_SZ) ? t + 1 : t;
    if (tid < H_DIM) {
      const unsigned short* gx = gx_base + (size_t)tn * G3;
      pr = bf2f(gx[tid]);
      pz = bf2f(gx[tid + 128]);
      pn = bf2f(gx[tid + 256]);
    }

    // gates_h via MFMA: two passes (h_hi, h_lo) accumulate into acc.
    f32x4 acc[6];
#pragma unroll
    for (int j = 0; j < 6; ++j) acc[j] = (f32x4){0.f, 0.f, 0.f, 0.f};
#pragma unroll
    for (int kt = 0; kt < 4; ++kt) {
      const bf16x8 ah = *(const bf16x8*)&h_hi[kt * 32 + quad * 8];
      const bf16x8 al = *(const bf16x8*)&h_lo[kt * 32 + quad * 8];
#pragma unroll
      for (int j = 0; j < 6; ++j) {
        acc[j] =
            __builtin_amdgcn_mfma_f32_16x16x32_bf16(ah, wf[j][kt], acc[j], 0, 0, 0);
        acc[j] =
            __builtin_amdgcn_mfma_f32_16x16x32_bf16(al, wf[j][kt], acc[j], 0, 0, 0);
      }
    }
    // Every lane holds gates_h[cb*16+m16] (all D rows equal); 16 lanes/quad
    // deposit each colblock (consecutive floats -> conflict-free).
#pragma unroll
    for (int j = 0; j < 6; ++j)
      if (quad == (j & 3)) part[(wave * 6 + j) * 16 + m16] = acc[j][0];
    __syncthreads();

    if (tid < H_DIM) {
      const float ghr = part[tid] + bh0;
      const float ghz = part[tid + 128] + bh1;
      const float ghn = part[tid + 256] + bh2;
      const float r = 1.f / (1.f + __expf(-(gxr + ghr)));
      const float z = 1.f / (1.f + __expf(-(gxz + ghz)));
      const float targ = gxn + r * ghn;
      const float e2 = __expf(-2.f * fabsf(targ));
      float nn = (1.f - e2) / (1.f + e2);
      nn = (targ < 0.f) ? -nn : nn;
      const float hn = (1.f - z) * nn + z * h_old;
      const unsigned short hh = f2bf(hn);
      h_hi[tid] = hh;
      h_lo[tid] = f2bf(hn - bf2f(hh));
      h_old = hn;
      hn_prev = hn;
    }
    gxr = pr;
    gxz = pz;
    gxn = pn;
    __syncthreads();
  }

  if (tid < H_DIM) {
    out_base[(size_t)(T_SZ - 1) * 2048 + tid] = hn_prev;
    out[OUT_HN_OFFSET + (size_t)b * 2048 + n * H_DIM + tid] = h_old;
  }
}

extern "C" void kernel_launch(void* const* d_in, const int* in_sizes, int n_in,
                              void* d_out, int out_size, void* d_ws,
                              size_t ws_size, hipStream_t stream) {
  const float* x    = (const float*)d_in[0]; // [B, T, N*I]
  const float* h0   = (const float*)d_in[1]; // [1, B, N*H]
  const float* w_ih = (const float*)d_in[2]; // [N, 3H, I]
  const float* w_hh = (const float*)d_in[3]; // [N, 3H, H]
  const float* b_ih = (const float*)d_in[4]; // [N, 3H]
  const float* b_hh = (const float*)d_in[5]; // [N, 3H]
  float* out = (float*)d_out;
  unsigned short* gates = (unsigned short*)d_ws; // [N][BT][3H] bf16 = 96 MB

  // Kernel A uses 122 KB LDS (full W_ih[n] resident): opt in past 64 KB.
  static bool lds_opt_in = false;
  if (!lds_opt_in) {
    (void)hipFuncSetAttribute(reinterpret_cast<const void*>(&gates_x_mfma),
                              hipFuncAttributeMaxDynamicSharedMemorySize,
                              (G3 + 64) * LDW * (int)sizeof(unsigned short));
    lds_opt_in = true;
  }

  dim3 gridA(16, 1, N_HEADS);
  gates_x_mfma<<<gridA, 256, (G3 + 64) * LDW * sizeof(unsigned short),
                 stream>>>(x, w_ih, b_ih, gates);
  gru_scan_kernel<<<256, 256, 0, stream>>>(h0, w_hh, b_hh, gates, out);
}

// Round 3
// 421.670 us; speedup vs baseline: 1.7209x; 1.6574x over previous
//
#include <hip/hip_runtime.h>
#include <cstdint>
#include <cmath>

#define N_HEADS 16
#define I_DIM 128
#define H_DIM 128
#define B_SZ 16
#define T_SZ 512
#define G3 384           // 3*H
#define BT (B_SZ * T_SZ) // 8192
#define LDW 136          // padded LDS row stride in bf16 (128+8), keeps 16B align
#define OUT_HN_OFFSET ((size_t)B_SZ * T_SZ * (N_HEADS * H_DIM)) // 16777216
#define CHUNK 8
#define NCHUNK (T_SZ / CHUNK) // 64

typedef __attribute__((ext_vector_type(8))) short bf16x8;
typedef __attribute__((ext_vector_type(4))) float f32x4;

static __device__ __forceinline__ unsigned short f2bf(float f) {
  unsigned int u = __float_as_uint(f);
  unsigned int r = (u + 0x7FFFu + ((u >> 16) & 1u)) >> 16; // RNE
  return (unsigned short)r;
}
static __device__ __forceinline__ float bf2f(unsigned short s) {
  return __uint_as_float((unsigned int)s << 16);
}
static __device__ __forceinline__ uint2 pack4(float4 v) {
  uint2 p;
  p.x = (unsigned int)f2bf(v.x) | ((unsigned int)f2bf(v.y) << 16);
  p.y = (unsigned int)f2bf(v.z) | ((unsigned int)f2bf(v.w) << 16);
  return p;
}
static __device__ __forceinline__ bf16x8 pack8(float4 a, float4 b) {
  union { uint2 u[2]; bf16x8 v; } r;
  r.u[0] = pack4(a);
  r.u[1] = pack4(b);
  return r.v;
}

// ---------------------------------------------------------------------------
// Kernel A (unchanged — working, ~110us): bf16 MFMA GEMM for gates_x.
// ---------------------------------------------------------------------------
__global__ __launch_bounds__(256) void gates_x_mfma(
    const float* __restrict__ x, const float* __restrict__ w_ih,
    const float* __restrict__ b_ih, unsigned short* __restrict__ gates) {
  const int n = blockIdx.z;
  const int grp = blockIdx.x; // 0..15, 8 tiles of 64 bt-rows each
  const int tid = threadIdx.x;
  const int wave = tid >> 6;
  const int lane = tid & 63;
  const int m16 = lane & 15;
  const int quad = lane >> 4;

  extern __shared__ __align__(16) unsigned short lds_pool[];
  unsigned short* Ws = lds_pool;            // G3*LDW ushorts = 104,448 B
  unsigned short* Xs = lds_pool + G3 * LDW; // 64*LDW ushorts =  17,408 B

  const int xrow = tid >> 2;
  const int xq = tid & 3;

  float4 xf[8];
  {
    const float4* xg =
        (const float4*)(x + (size_t)(grp * 512 + xrow) * 2048 + n * I_DIM) +
        xq * 8;
#pragma unroll
    for (int i = 0; i < 8; ++i) xf[i] = xg[i];
  }

  {
    const float4* wsrc = (const float4*)(w_ih + (size_t)n * G3 * I_DIM);
#pragma unroll
    for (int i = 0; i < 48; ++i) {
      const int idx = i * 256 + tid; // f4 index
      *(uint2*)&Ws[(idx >> 5) * LDW + (idx & 31) * 4] = pack4(wsrc[idx]);
    }
  }

  float bias[3][8];
#pragma unroll
  for (int gb = 0; gb < 3; ++gb)
#pragma unroll
    for (int j = 0; j < 8; ++j)
      bias[gb][j] = b_ih[n * G3 + gb * 128 + j * 16 + m16];

  for (int tile = 0; tile < 8; ++tile) {
    const int bt0 = grp * 512 + tile * 64;

    __syncthreads();
#pragma unroll
    for (int i = 0; i < 8; ++i)
      *(uint2*)&Xs[xrow * LDW + xq * 32 + i * 4] = pack4(xf[i]);
    __syncthreads();

    if (tile < 7) {
      const float4* xg =
          (const float4*)(x + (size_t)(bt0 + 64 + xrow) * 2048 + n * I_DIM) +
          xq * 8;
#pragma unroll
      for (int i = 0; i < 8; ++i) xf[i] = xg[i];
    }

#pragma unroll
    for (int gb = 0; gb < 3; ++gb) {
      f32x4 acc[8];
#pragma unroll
      for (int j = 0; j < 8; ++j) acc[j] = (f32x4){0.f, 0.f, 0.f, 0.f};

#pragma unroll
      for (int kt = 0; kt < 4; ++kt) {
        const bf16x8 afrag =
            *(const bf16x8*)&Xs[(wave * 16 + m16) * LDW + kt * 32 + quad * 8];
#pragma unroll
        for (int j = 0; j < 8; ++j) {
          const bf16x8 bfrag =
              *(const bf16x8*)&Ws[(gb * 128 + j * 16 + m16) * LDW + kt * 32 +
                                  quad * 8];
          acc[j] = __builtin_amdgcn_mfma_f32_16x16x32_bf16(afrag, bfrag,
                                                           acc[j], 0, 0, 0);
        }
      }

#pragma unroll
      for (int j = 0; j < 8; ++j) {
        const int g = gb * 128 + j * 16 + m16;
#pragma unroll
        for (int r = 0; r < 4; ++r) {
          const int bt = bt0 + wave * 16 + quad * 4 + r;
          gates[((size_t)n * BT + bt) * G3 + g] =
              f2bf(acc[j][r] + bias[gb][j]);
        }
      }
    }
  }
}

// ---------------------------------------------------------------------------
// Kernel B v4: latency-optimized MFMA scan. One WG (256 thr = 4 waves) per
// (b,n).
//
// R2 post-mortem: v3's 2730cy/step was the per-step __syncthreads vmcnt(0)
// drain of the gates HBM prefetch + out store (~500-900cy, x2 barriers) plus
// a cross-wave part[]-LDS round-trip. Fixes:
//  1. NO global ops in the steady-state step: gates staged per 8-step chunk
//     into double-buffered LDS (6KB); out values held in regs, stored once
//     per chunk. Step barriers drain nothing.
//  2. Gate-column remap: wave w owns colblocks {2w,8+2w,16+2w,2w+1,...} so
//     r/z/n for its 32 h-elements land in ITS OWN lanes -> update reads acc
//     registers directly, no part[] round-trip, ONE barrier/step (h is
//     double-buffered: read h2[t&1], write h2[(t&1)^1]).
//  3. h_hi in even A-rows, h_lo in odd (per-lane parity on the ds_read
//     address): D row 4q = W.h_hi, row 4q+1 = W.h_lo for every quad ->
//     gh = acc[j][0]+acc[j][1]. 24 MFMA/step (was 48), chain depth 4.
// quad0 lanes update h[w*32+m16] (acc 0..2), quad1 lanes h[w*32+16+m16]
// (acc 3..5); quads 2,3 idle in the update (redundant MFMA rows).
// acc is indexed statically everywhere (runtime-indexed ext_vector arrays
// go to scratch); quad-select via ternaries.
// ---------------------------------------------------------------------------
__global__ __launch_bounds__(256, 1) void gru_scan_kernel(
    const float* __restrict__ h0, const float* __restrict__ w_hh,
    const float* __restrict__ b_hh, const unsigned short* __restrict__ gates,
    float* __restrict__ out) {
  const int b = blockIdx.x >> 4;
  const int n = blockIdx.x & 15;
  const int tid = threadIdx.x;
  const int wave = tid >> 6;
  const int lane = tid & 63;
  const int m16 = lane & 15;
  const int quad = lane >> 4;

  __shared__ __align__(16) unsigned short h2[2][2][H_DIM];    // [buf][hi|lo]
  __shared__ __align__(16) unsigned short gbuf[2][CHUNK * G3]; // 2 x 6 KB

  // Register-resident W_hh bf16 B-fragments (layout identical to kernel A's
  // verified bfrag): lane(quad,m16) holds W[g][kt*32+quad*8 ..+8].
  // j -> colblock: {2w, 8+2w, 16+2w, 2w+1, 9+2w, 17+2w}  (r0,z0,n0,r1,z1,n1)
  bf16x8 wf[6][4];
  {
    const int cb0 = 2 * wave;
    const int cbs[6] = {cb0, 8 + cb0, 16 + cb0, cb0 + 1, 9 + cb0, 17 + cb0};
#pragma unroll
    for (int j = 0; j < 6; ++j) {
      const int g = cbs[j] * 16 + m16;
      const float4* wr = (const float4*)(w_hh + ((size_t)n * G3 + g) * H_DIM);
#pragma unroll
      for (int kt = 0; kt < 4; ++kt)
        wf[j][kt] = pack8(wr[kt * 8 + quad * 2], wr[kt * 8 + quad * 2 + 1]);
    }
  }

  const bool upd = quad < 2;                    // updating lanes (128 total)
  const int elem = wave * 32 + quad * 16 + m16; // h element owned (if upd)

  float bh_r = 0.f, bh_z = 0.f, bh_n = 0.f, h_old = 0.f;
  if (upd) {
    bh_r = b_hh[n * G3 + elem];
    bh_z = b_hh[n * G3 + elem + 128];
    bh_n = b_hh[n * G3 + elem + 256];
    h_old = h0[(size_t)b * 2048 + n * H_DIM + elem];
    const unsigned short hh = f2bf(h_old);
    h2[0][0][elem] = hh;
    h2[0][1][elem] = f2bf(h_old - bf2f(hh));
  }

  const unsigned short* gx_base =
      gates + ((size_t)n * BT + (size_t)b * T_SZ) * G3;
  float* out_base = out + (size_t)b * T_SZ * 2048 + n * H_DIM;

  // Prologue: stage gates chunk 0 (3072 ushorts = 768 uint2, coalesced).
  uint2 pf0, pf1, pf2;
  {
    const uint2* gsrc = (const uint2*)gx_base;
    pf0 = gsrc[tid];
    pf1 = gsrc[256 + tid];
    pf2 = gsrc[512 + tid];
    uint2* gd = (uint2*)gbuf[0];
    gd[tid] = pf0;
    gd[256 + tid] = pf1;
    gd[512 + tid] = pf2;
  }
  __syncthreads();

  float oreg[CHUNK];

  for (int c = 0; c < NCHUNK; ++c) {
    const int gb = c & 1;

    // Issue next chunk's global loads; they retire under this chunk's steps
    // (first step-barrier drains them — once per 8 steps, not per step).
    if (c + 1 < NCHUNK) {
      const uint2* gsrc =
          (const uint2*)(gx_base + (size_t)(c + 1) * CHUNK * G3);
      pf0 = gsrc[tid];
      pf1 = gsrc[256 + tid];
      pf2 = gsrc[512 + tid];
    }

#pragma unroll
    for (int s = 0; s < CHUNK; ++s) {
      const int rb = s & 1;      // chunk length even -> parity restarts at 0
      const int wb = rb ^ 1;

      // gates_x for this step (LDS, issued early to hide under MFMA).
      float gxr = 0.f, gxz = 0.f, gxn = 0.f;
      if (upd) {
        const unsigned short* gx = &gbuf[gb][s * G3 + elem];
        gxr = bf2f(gx[0]);
        gxz = bf2f(gx[128]);
        gxn = bf2f(gx[256]);
      }

      // gates_h via MFMA: even A-rows = h_hi, odd = h_lo.
      f32x4 acc[6];
#pragma unroll
      for (int j = 0; j < 6; ++j) acc[j] = (f32x4){0.f, 0.f, 0.f, 0.f};
#pragma unroll
      for (int kt = 0; kt < 4; ++kt) {
        const bf16x8 av =
            *(const bf16x8*)&h2[rb][m16 & 1][kt * 32 + quad * 8];
#pragma unroll
        for (int j = 0; j < 6; ++j)
          acc[j] = __builtin_amdgcn_mfma_f32_16x16x32_bf16(av, wf[j][kt],
                                                           acc[j], 0, 0, 0);
      }

      // D[4q] = W.h_hi, D[4q+1] = W.h_lo  (valid in every quad).
      const float s0 = acc[0][0] + acc[0][1];
      const float s1 = acc[1][0] + acc[1][1];
      const float s2 = acc[2][0] + acc[2][1];
      const float s3 = acc[3][0] + acc[3][1];
      const float s4 = acc[4][0] + acc[4][1];
      const float s5 = acc[5][0] + acc[5][1];

      if (upd) {
        const float ghr = (quad ? s3 : s0) + bh_r;
        const float ghz = (quad ? s4 : s1) + bh_z;
        const float ghn = (quad ? s5 : s2) + bh_n;
        const float r = 1.f / (1.f + __expf(-(gxr + ghr)));
        const float z = 1.f / (1.f + __expf(-(gxz + ghz)));
        const float targ = gxn + r * ghn;
        const float e2 = __expf(-2.f * fabsf(targ));
        float nn = (1.f - e2) / (1.f + e2);
        nn = (targ < 0.f) ? -nn : nn;
        const float hn = (1.f - z) * nn + z * h_old;
        const unsigned short hh = f2bf(hn);
        h2[wb][0][elem] = hh;
        h2[wb][1][elem] = f2bf(hn - bf2f(hh));
        h_old = hn;
        oreg[s] = hn;
      }

      // Stage next chunk into the other gbuf before the last step-barrier.
      if (s == CHUNK - 1 && c + 1 < NCHUNK) {
        uint2* gd = (uint2*)gbuf[gb ^ 1];
        gd[tid] = pf0;
        gd[256 + tid] = pf1;
        gd[512 + tid] = pf2;
      }
      __syncthreads();
    }

    // Batched out stores (retire under next chunk; drained once per chunk).
    if (upd) {
#pragma unroll
      for (int s = 0; s < CHUNK; ++s)
        out_base[(size_t)(c * CHUNK + s) * 2048 + elem] = oreg[s];
    }
  }

  if (upd) {
    out[OUT_HN_OFFSET + (size_t)b * 2048 + n * H_DIM + elem] = h_old;
  }
}

extern "C" void kernel_launch(void* const* d_in, const int* in_sizes, int n_in,
                              void* d_out, int out_size, void* d_ws,
                              size_t ws_size, hipStream_t stream) {
  const float* x    = (const float*)d_in[0]; // [B, T, N*I]
  const float* h0   = (const float*)d_in[1]; // [1, B, N*H]
  const float* w_ih = (const float*)d_in[2]; // [N, 3H, I]
  const float* w_hh = (const float*)d_in[3]; // [N, 3H, H]
  const float* b_ih = (const float*)d_in[4]; // [N, 3H]
  const float* b_hh = (const float*)d_in[5]; // [N, 3H]
  float* out = (float*)d_out;
  unsigned short* gates = (unsigned short*)d_ws; // [N][BT][3H] bf16 = 96 MB

  // Kernel A uses 122 KB LDS (full W_ih[n] resident): opt in past 64 KB.
  static bool lds_opt_in = false;
  if (!lds_opt_in) {
    (void)hipFuncSetAttribute(reinterpret_cast<const void*>(&gates_x_mfma),
                              hipFuncAttributeMaxDynamicSharedMemorySize,
                              (G3 + 64) * LDW * (int)sizeof(unsigned short));
    lds_opt_in = true;
  }

  dim3 gridA(16, 1, N_HEADS);
  gates_x_mfma<<<gridA, 256, (G3 + 64) * LDW * sizeof(unsigned short),
                 stream>>>(x, w_ih, b_ih, gates);
  gru_scan_kernel<<<256, 256, 0, stream>>>(h0, w_hh, b_hh, gates, out);
}